// Round 10
// baseline (34.532 us; speedup 1.0000x reference)
//
#include <hip/hip_runtime.h>
#include <math.h>

#define N_HI 192      // IMAGE_RES_OUT * IMAGE_UPSCALE
#define F_HI 128      // FREQ_RES_OUT * FREQ_UPSCALE
#define NOUT 96
#define FOUT 32
#define NSEG 4        // 3 window buckets (pitch 32) + 1 full-eval fallback
#define MAXP 208      // 192 survivors + per-seg pad/align slack (<=204 used)

__device__ __forceinline__ float fast_exp2(float x) {
#if __has_builtin(__builtin_amdgcn_exp2f)
    return __builtin_amdgcn_exp2f(x);
#else
    return exp2f(x);
#endif
}
__device__ __forceinline__ float fast_rcp(float x) {
#if __has_builtin(__builtin_amdgcn_rcpf)
    return __builtin_amdgcn_rcpf(x);
#else
    return 1.0f / x;
#endif
}

__global__ __launch_bounds__(256) void cube_sim_kernel(
    const float* __restrict__ p_inc, const float* __restrict__ p_rot,
    const float* __restrict__ p_lb,  const float* __restrict__ p_vs,
    const float* __restrict__ p_vmax,const float* __restrict__ p_rc,
    const float* __restrict__ p_Rd,  const float* __restrict__ p_hz,
    const float* __restrict__ freqs, float* __restrict__ out)
{
    const int jo   = blockIdx.x;
    const int io   = blockIdx.y;
    const int tid  = threadIdx.x;
    const int col  = tid >> 6;        // wave id = column in the 2x2 hi-res patch
    const int lane = tid & 63;

    __shared__ alignas(16) float2 pairs[4][MAXP];  // bucket-segmented (u, nL)
    __shared__ float accb[4][3][64];  // per-(col,bucket) window accumulators
                                      // written ONCE via plain store: no LDS RMW,
                                      // immune to cross-bucket reordering (r8 bug)

    // ---- uniform scalar setup (fast intrinsics) ----
    const float FOV    = 500.0f;
    const float C_KMS  = 299792.458f;
    const float F_REST = 230.538f;
    const float LOG2E  = 1.4426950408889634f;

    const float inc    = *p_inc;
    const float rot    = *p_rot;
    const float lb     = *p_lb;
    const float vshift = *p_vs;
    const float vmax   = *p_vmax;
    const float rc     = *p_rc;
    const float Rd     = *p_Rd;
    const float hz     = *p_hz;
    const float f0     = freqs[0];
    const float f_last = freqs[FOUT - 1];

    const float cr = __cosf(rot), sr = __sinf(rot);
    const float ci = __cosf(inc), si = __sinf(inc);

    const float dx     = 2.0f * FOV / (float)(N_HI - 1);
    const float Rmin   = 0.1f * (2.0f * FOV / (float)N_HI);
    const float rc2pm  = rc * rc + Rmin * Rmin;
    const float sig_sq = lb * lb;
    const float pc2    = (0.5f * fast_rcp(sig_sq)) * LOG2E;   // +Gaussian coeff (log2)
    const float kR     = LOG2E * fast_rcp(Rd);                // intensity radial coeff
    const float kz     = 0.5f * LOG2E * fast_rcp(hz * hz);    // intensity vertical coeff
    const float THR_P  = 13.2877f;        // -log2(1e-4): survivor cutoff (positive form)

    const float fstep = (f_last - f0) * (1.0f / (float)(F_HI - 1));
    const float vlA   = C_KMS * (1.0f - f0 * (1.0f / F_REST)) - vshift;  // vlab(0)
    const float vlB   = -C_KMS * fstep * (1.0f / F_REST);                // vlab step / ch
    const float Dv    = 64.0f * vlB;
    const float c3    = 2.0f * Dv * pc2;                      // full-path delta coeffs
    const float c4    = Dv * Dv * pc2;                        // e1 = e0 + c3*d0 + c4
    const float invB  = fast_rcp(vlB);
    const float cA    = -vlA * invB;                          // fc = vl*invB + cA
    const float cgp   = pc2 * vlB * vlB;                      // +coeff per channel^2
    const float s     = sqrtf(cgp);                           // u-trick scale
    const float s32   = 32.0f * s;
    // pitch-32 window fit: 4.85-sigma support half-width must be <= 15.5 ch
    const float margin = 4.85f * lb * fabsf(invB);
    const bool  win_ok = (margin <= 15.5f);

    // ---- zero this wave's accumulators (wave-private, store-only) ----
    #pragma unroll
    for (int t = 0; t < 3; ++t) accb[col][t][lane] = 0.0f;

    // ---- phase 1: column voxels -> bucket-classified survivor records ----
    const int i = (io << 1) + (col >> 1);
    const int j = (jo << 1) + (col & 1);
    const float x  = -FOV + dx * (float)i;
    const float y  = -FOV + dx * (float)j;
    const float rx = cr * x - sr * y;          // z-independent
    const float y1 = sr * x + cr * y;
    const float ciy1 = ci * y1, siy1 = si * y1;
    const float nsvrx = -si * vmax * rx;
    const float rx2   = rx * rx;
    const float rx2c  = rx2 + rc2pm;

    float u_c[3], L_c[3];
    int   bk_c[3];
    #pragma unroll
    for (int c = 0; c < 3; ++c) {
        const float z  = -FOV + dx * (float)(c * 64 + lane);
        const float ry = __builtin_fmaf(-si, z, ciy1);
        const float rz = __builtin_fmaf( ci, z, siy1);
        const float ry2 = ry * ry;
        const float R  = sqrtf(__builtin_fmaf(ry, ry, rx2));
        const float nL = __builtin_fmaf(R, kR, rz * rz * kz);  // -log2 intensity (>=0)
        const float inv  = __frsqrt_rn(ry2 + rx2c);
        const float vlos = nsvrx * inv;
        const float fc   = __builtin_fmaf(vlos, invB, cA);
        int bk = 7;                                  // 7 = dead
        float uu;
        if (win_ok) {
            int k = (int)rintf(__builtin_fmaf(fc, 0.03125f, -0.984375f)); // (fc-31.5)/32
            k = min(max(k, 0), 2);
            if (nL <= THR_P) bk = k;
            uu = __builtin_fmaf(-(float)k, s32, s * fc);   // u = s*(fc - 32k)
        } else {
            if (nL <= THR_P) bk = 3;
            uu = vlos;
        }
        u_c[c] = uu; L_c[c] = nL; bk_c[c] = bk;
    }

    // pass A: ballots once, keep masks; per-segment counts
    unsigned long long m_ck[3][NSEG];
    int cnt[NSEG];
    #pragma unroll
    for (int k = 0; k < NSEG; ++k) cnt[k] = 0;
    #pragma unroll
    for (int c = 0; c < 3; ++c)
        #pragma unroll
        for (int k = 0; k < NSEG; ++k) {
            const unsigned long long m = __ballot(bk_c[c] == k);
            m_ck[c][k] = m;
            cnt[k] += (int)__popcll(m);
        }

    // even-aligned segment bases (>=2 pad slots each)
    int base[NSEG];
    {
        int acc = 0;
        #pragma unroll
        for (int k = 0; k < NSEG; ++k) { base[k] = acc; acc += (cnt[k] + 3) & ~1; }
    }

    // pass B: scatter records (rank via mbcnt)
    {
        int run[NSEG];
        #pragma unroll
        for (int k = 0; k < NSEG; ++k) run[k] = 0;
        #pragma unroll
        for (int c = 0; c < 3; ++c)
            #pragma unroll
            for (int k = 0; k < NSEG; ++k) {
                const unsigned long long m = m_ck[c][k];
                if (bk_c[c] == k) {
                    const int rank = (int)__builtin_amdgcn_mbcnt_hi(
                        (unsigned)(m >> 32),
                        __builtin_amdgcn_mbcnt_lo((unsigned)m, 0u));
                    pairs[col][base[k] + run[k] + rank] = make_float2(u_c[c], L_c[c]);
                }
                run[k] += (int)__popcll(m);
            }
    }
    // dead pads (exp2 -> 0) so odd counts / float4 reads are safe
    #pragma unroll
    for (int k = 0; k < NSEG; ++k)
        if (lane < 2) pairs[col][base[k] + cnt[k] + lane] = make_float2(0.0f, 100000.0f);

    // ---- phase 2: per-bucket windowed eval: sub+fma+exp+add per survivor ----
    const float wl = s * (float)lane;
    #pragma unroll
    for (int k = 0; k < 3; ++k) {
        const int nI = (cnt[k] + 1) >> 1;
        if (nI > 0) {
            const float4* pp = reinterpret_cast<const float4*>(&pairs[col][base[k]]);
            float aw = 0.0f;
            for (int it = 0; it < nI; ++it) {
                const float4 q = pp[it];             // wave-uniform broadcast b128
                const float dA = wl - q.x;
                const float dB = wl - q.z;
                aw += fast_exp2(-__builtin_fmaf(dA, dA, q.y));
                aw += fast_exp2(-__builtin_fmaf(dB, dB, q.w));
            }
            accb[col][k][lane] = aw;                 // plain store, written once
        }
    }
    // segment 3: full 128-channel path (only if margin doesn't fit a window;
    // then buckets 0-2 are empty -> reuse rows 0 (ch lane) and 2 (ch 64+lane))
    {
        const int nI = (cnt[3] + 1) >> 1;
        if (nI > 0) {
            const float vlab0 = vlA + vlB * (float)lane;
            const float4* pp = reinterpret_cast<const float4*>(&pairs[col][base[3]]);
            float a0 = 0.0f, a1 = 0.0f;
            for (int it = 0; it < nI; ++it) {
                const float4 q = pp[it];
                {
                    const float d0 = vlab0 - q.x;
                    const float e0 = __builtin_fmaf(d0, d0 * pc2, q.y);
                    a0 += fast_exp2(-e0);
                    a1 += fast_exp2(-(e0 + __builtin_fmaf(d0, c3, c4)));
                }
                {
                    const float d0 = vlab0 - q.z;
                    const float e0 = __builtin_fmaf(d0, d0 * pc2, q.w);
                    a0 += fast_exp2(-e0);
                    a1 += fast_exp2(-(e0 + __builtin_fmaf(d0, c3, c4)));
                }
            }
            accb[col][0][lane] = a0;    // channel lane      = 32*0 + lane
            accb[col][2][lane] = a1;    // channel 64 + lane = 32*2 + lane
        }
    }
    __syncthreads();

    // ---- phase 3: guarded fold of overlapping windows -> 32 outputs ----
    if (tid < FOUT) {
        float ssum = 0.0f;
        #pragma unroll
        for (int fu = 0; fu < 4; ++fu) {
            const int ch = 4 * tid + fu;
            #pragma unroll
            for (int k = 0; k < 3; ++k) {
                const int d = ch - 32 * k;
                if ((unsigned)d < 64u) {
                    #pragma unroll
                    for (int c2 = 0; c2 < 4; ++c2)
                        ssum += accb[c2][k][d];
                }
            }
        }
        const float norm16 = __frsqrt_rn(2.0f * 3.14159265358979f * sig_sq) * (1.0f / 16.0f);
        out[tid * (NOUT * NOUT) + io * NOUT + jo] = ssum * norm16;
    }
}

extern "C" void kernel_launch(void* const* d_in, const int* in_sizes, int n_in,
                              void* d_out, int out_size, void* d_ws, size_t ws_size,
                              hipStream_t stream) {
    const float* p_inc  = (const float*)d_in[0];
    const float* p_rot  = (const float*)d_in[1];
    const float* p_lb   = (const float*)d_in[2];
    const float* p_vs   = (const float*)d_in[3];
    const float* p_vmax = (const float*)d_in[4];
    const float* p_rc   = (const float*)d_in[5];
    const float* p_Rd   = (const float*)d_in[6];
    const float* p_hz   = (const float*)d_in[7];
    const float* freqs  = (const float*)d_in[8];
    float* out = (float*)d_out;

    dim3 grid(NOUT, NOUT);
    dim3 block(256);
    cube_sim_kernel<<<grid, block, 0, stream>>>(p_inc, p_rot, p_lb, p_vs,
                                                p_vmax, p_rc, p_Rd, p_hz,
                                                freqs, out);
}

// Round 11
// 26.400 us; speedup vs baseline: 1.3080x; 1.3080x over previous
//
#include <hip/hip_runtime.h>
#include <math.h>

#define N_HI 192      // IMAGE_RES_OUT * IMAGE_UPSCALE
#define NOUT 96
#define FOUT 32
#define MAXP 194      // 192 records max + 1 pad + slack

__device__ __forceinline__ float fast_exp2(float x) {
#if __has_builtin(__builtin_amdgcn_exp2f)
    return __builtin_amdgcn_exp2f(x);
#else
    return exp2f(x);
#endif
}
__device__ __forceinline__ float fast_rcp(float x) {
#if __has_builtin(__builtin_amdgcn_rcpf)
    return __builtin_amdgcn_rcpf(x);
#else
    return 1.0f / x;
#endif
}
__device__ __forceinline__ int lane_rank(unsigned long long m) {
    return (int)__builtin_amdgcn_mbcnt_hi((unsigned)(m >> 32),
            __builtin_amdgcn_mbcnt_lo((unsigned)m, 0u));
}

__global__ __launch_bounds__(256) void cube_sim_kernel(
    const float* __restrict__ p_inc, const float* __restrict__ p_rot,
    const float* __restrict__ p_lb,  const float* __restrict__ p_vs,
    const float* __restrict__ p_vmax,const float* __restrict__ p_rc,
    const float* __restrict__ p_Rd,  const float* __restrict__ p_hz,
    const float* __restrict__ freqs, float* __restrict__ out)
{
    const int jo   = blockIdx.x;
    const int io   = blockIdx.y;
    const int tid  = threadIdx.x;
    const int col  = tid >> 6;        // wave id = column in the 2x2 hi-res patch
    const int lane = tid & 63;
    const int half = lane >> 5;       // which record of a pair this lane serves
    const float chf = (float)(lane & 31);   // output channel this lane owns

    __shared__ alignas(16) float2 pairs[4][MAXP];  // compacted (qo, qnL)
    __shared__ float acc_s[4][2][32];              // store-once, no RMW (r8 lesson)

    // ---- uniform scalar setup ----
    const float FOV    = 500.0f;
    const float C_KMS  = 299792.458f;
    const float F_REST = 230.538f;
    const float LOG2E  = 1.4426950408889634f;
    const float LN2    = 0.6931471805599453f;

    const float inc    = *p_inc;
    const float rot    = *p_rot;
    const float lb     = *p_lb;
    const float vshift = *p_vs;
    const float vmax   = *p_vmax;
    const float rc     = *p_rc;
    const float Rd     = *p_Rd;
    const float hz     = *p_hz;
    const float f0     = freqs[0];
    const float f_last = freqs[FOUT - 1];

    const float cr = __cosf(rot), sr = __sinf(rot);
    const float ci = __cosf(inc), si = __sinf(inc);

    const float dx     = 2.0f * FOV / (float)(N_HI - 1);
    const float Rmin   = 0.1f * (2.0f * FOV / (float)N_HI);
    const float rc2pm  = rc * rc + Rmin * Rmin;
    const float sig_sq = lb * lb;
    const float pc2    = (0.5f * fast_rcp(sig_sq)) * LOG2E;   // Gaussian coeff (log2, km/s)
    const float kR     = LOG2E * fast_rcp(Rd);
    const float kz     = 0.5f * LOG2E * fast_rcp(hz * hz);
    const float THR_P  = 13.2877f;        // -log2(1e-4): survivor cutoff

    const float fstep = (f_last - f0) * (1.0f / (float)(127.0f));      // F_HI-1
    const float vlA   = C_KMS * (1.0f - f0 * (1.0f / F_REST)) - vshift;
    const float vlB   = -C_KMS * fstep * (1.0f / F_REST);              // km/s per subch
    const float invB  = fast_rcp(vlB);
    const float cA    = -vlA * invB;                   // fc = vl*invB + cA  (subch units)
    const float cgp   = pc2 * vlB * vlB;               // exponent coeff per subch^2
    const float s     = sqrtf(cgp);

    // box-average moment match: sigma_e^2 = sigma^2 + 1.25 (subch^2), in log2 form
    const bool  use_box = (cgp <= 0.22f);              // sigma_subch >= ~1.8: approx valid
    const float cgp_e = cgp * fast_rcp(1.0f + 2.5f * LN2 * cgp);
    const float s_e   = sqrtf(cgp_e);
    const float dL    = 0.5f * __log2f(1.0f + 2.5f * LN2 * cgp);  // amplitude sigma/sigma_e

    const float sSel = use_box ? s_e : s;
    const float qoff = use_box ? 1.5f : 0.0f;          // stencil center offset
    const float dLs  = use_box ? dL : 0.0f;

    // ---- phase 1: column voxels -> compacted records (single segment) ----
    const int i = (io << 1) + (col >> 1);
    const int j = (jo << 1) + (col & 1);
    const float x  = -FOV + dx * (float)i;
    const float y  = -FOV + dx * (float)j;
    const float rx = cr * x - sr * y;
    const float y1 = sr * x + cr * y;
    const float ciy1 = ci * y1, siy1 = si * y1;
    const float nsvrx = -si * vmax * rx;
    const float rx2   = rx * rx;
    const float rx2c  = rx2 + rc2pm;

    int cnt = 0;
    #pragma unroll
    for (int c = 0; c < 3; ++c) {
        const float z  = -FOV + dx * (float)(c * 64 + lane);
        const float ry = __builtin_fmaf(-si, z, ciy1);
        const float rz = __builtin_fmaf( ci, z, siy1);
        const float ry2 = ry * ry;
        const float R  = sqrtf(__builtin_fmaf(ry, ry, rx2));
        const float nL = __builtin_fmaf(R, kR, rz * rz * kz);  // -log2 intensity (>=0)
        const float inv  = __frsqrt_rn(ry2 + rx2c);
        const float vlos = nsvrx * inv;
        const float fc   = __builtin_fmaf(vlos, invB, cA);     // center, subch units
        const bool alive = (nL <= THR_P);
        const unsigned long long m = __ballot(alive);
        if (alive) {
            const float qo = sSel * (qoff - fc);
            pairs[col][cnt + lane_rank(m)] = make_float2(qo, nL + dLs);
        }
        cnt += (int)__popcll(m);
    }
    if (lane == 0) pairs[col][cnt] = make_float2(0.0f, 100000.0f);  // dead pad

    // ---- phase 2: 2 records/iter; lane serves record `half` over out-ch (lane&31) ----
    const float w4 = (4.0f * sSel) * chf;   // sSel * 4*chout
    const int nIter = (cnt + 1) >> 1;
    const float2* bp = reinterpret_cast<const float2*>(
        reinterpret_cast<const char*>(&pairs[col][0]) + (half << 3));
    float a0 = 0.0f, a1 = 0.0f;
    if (use_box) {
        int it = 0;
        for (; it + 2 <= nIter; it += 2) {
            const float2 qA = bp[2 * it];        // record 2it+half (broadcast per half)
            const float2 qB = bp[2 * it + 2];    // record 2(it+1)+half
            const float dA = w4 + qA.x;
            const float dB = w4 + qB.x;
            a0 += fast_exp2(-__builtin_fmaf(dA, dA, qA.y));
            a1 += fast_exp2(-__builtin_fmaf(dB, dB, qB.y));
        }
        if (it < nIter) {
            const float2 qA = bp[2 * it];
            const float dA = w4 + qA.x;
            a0 += fast_exp2(-__builtin_fmaf(dA, dA, qA.y));
        }
    } else {
        // exact 4-subchannel path (only for narrow line widths)
        for (int it = 0; it < nIter; ++it) {
            const float2 q = bp[2 * it];
            const float db = w4 + q.x;
            #pragma unroll
            for (int fu = 0; fu < 4; ++fu) {
                const float d = __builtin_fmaf((float)fu, sSel, db);
                a0 += fast_exp2(-__builtin_fmaf(d, d, q.y));
            }
        }
    }
    acc_s[col][half][lane & 31] = a0 + a1;      // plain store, written once
    __syncthreads();

    // ---- phase 3: fold 4 cols x 2 halves -> 32 outputs ----
    if (tid < FOUT) {
        float ssum = 0.0f;
        #pragma unroll
        for (int c2 = 0; c2 < 4; ++c2)
            #pragma unroll
            for (int h = 0; h < 2; ++h)
                ssum += acc_s[c2][h][tid];
        const float normc = __frsqrt_rn(2.0f * 3.14159265358979f * sig_sq)
                          * (use_box ? 0.25f : 0.0625f);   // norm/4 (box) or norm/16 (exact)
        out[tid * (NOUT * NOUT) + io * NOUT + jo] = ssum * normc;
    }
}

extern "C" void kernel_launch(void* const* d_in, const int* in_sizes, int n_in,
                              void* d_out, int out_size, void* d_ws, size_t ws_size,
                              hipStream_t stream) {
    const float* p_inc  = (const float*)d_in[0];
    const float* p_rot  = (const float*)d_in[1];
    const float* p_lb   = (const float*)d_in[2];
    const float* p_vs   = (const float*)d_in[3];
    const float* p_vmax = (const float*)d_in[4];
    const float* p_rc   = (const float*)d_in[5];
    const float* p_Rd   = (const float*)d_in[6];
    const float* p_hz   = (const float*)d_in[7];
    const float* freqs  = (const float*)d_in[8];
    float* out = (float*)d_out;

    dim3 grid(NOUT, NOUT);
    dim3 block(256);
    cube_sim_kernel<<<grid, block, 0, stream>>>(p_inc, p_rot, p_lb, p_vs,
                                                p_vmax, p_rc, p_Rd, p_hz,
                                                freqs, out);
}

// Round 12
// 26.280 us; speedup vs baseline: 1.3140x; 1.0046x over previous
//
#include <hip/hip_runtime.h>
#include <math.h>

#define N_HI 192      // IMAGE_RES_OUT * IMAGE_UPSCALE
#define NOUT 96
#define FOUT 32
#define MAXP 224      // survivors + 4 segs * 8 pads
#define DEADB 7

__device__ __forceinline__ float fast_exp2(float x) {
#if __has_builtin(__builtin_amdgcn_exp2f)
    return __builtin_amdgcn_exp2f(x);
#else
    return exp2f(x);
#endif
}
__device__ __forceinline__ float fast_rcp(float x) {
#if __has_builtin(__builtin_amdgcn_rcpf)
    return __builtin_amdgcn_rcpf(x);
#else
    return 1.0f / x;
#endif
}
__device__ __forceinline__ int lane_rank(unsigned long long m) {
    return (int)__builtin_amdgcn_mbcnt_hi((unsigned)(m >> 32),
            __builtin_amdgcn_mbcnt_lo((unsigned)m, 0u));
}

__global__ __launch_bounds__(256) void cube_sim_kernel(
    const float* __restrict__ p_inc, const float* __restrict__ p_rot,
    const float* __restrict__ p_lb,  const float* __restrict__ p_vs,
    const float* __restrict__ p_vmax,const float* __restrict__ p_rc,
    const float* __restrict__ p_Rd,  const float* __restrict__ p_hz,
    const float* __restrict__ freqs, float* __restrict__ out)
{
    const int jo   = blockIdx.x;
    const int io   = blockIdx.y;
    const int tid  = threadIdx.x;
    const int col  = tid >> 6;        // wave id = column in the 2x2 hi-res patch
    const int lane = tid & 63;
    const int g    = lane >> 4;       // record-group (window path)
    const int l16  = lane & 15;       // channel within 16-wide window
    const int half = lane >> 5;       // record parity (fallback path)
    const int l32  = lane & 31;       // channel (fallback path)

    __shared__ alignas(16) float2 pairs[4][MAXP];  // segment-compacted (qo, nL')
    __shared__ float accb[4][3][4][16];            // store-once accums (no LDS RMW)

    // ---- uniform scalar setup ----
    const float FOV    = 500.0f;
    const float C_KMS  = 299792.458f;
    const float F_REST = 230.538f;
    const float LOG2E  = 1.4426950408889634f;
    const float LN2    = 0.6931471805599453f;

    const float inc    = *p_inc;
    const float rot    = *p_rot;
    const float lb     = *p_lb;
    const float vshift = *p_vs;
    const float vmax   = *p_vmax;
    const float rc     = *p_rc;
    const float Rd     = *p_Rd;
    const float hz     = *p_hz;
    const float f0     = freqs[0];
    const float f_last = freqs[FOUT - 1];

    const float cr = __cosf(rot), sr = __sinf(rot);
    const float ci = __cosf(inc), si = __sinf(inc);

    const float dx     = 2.0f * FOV / (float)(N_HI - 1);
    const float Rmin   = 0.1f * (2.0f * FOV / (float)N_HI);
    const float rc2pm  = rc * rc + Rmin * Rmin;
    const float sig_sq = lb * lb;
    const float pc2    = (0.5f * fast_rcp(sig_sq)) * LOG2E;
    const float kR     = LOG2E * fast_rcp(Rd);
    const float kz     = 0.5f * LOG2E * fast_rcp(hz * hz);
    const float THR_P  = 13.2877f;        // -log2(1e-4) survivor cutoff

    const float fstep = (f_last - f0) * (1.0f / 127.0f);
    const float vlA   = C_KMS * (1.0f - f0 * (1.0f / F_REST)) - vshift;
    const float vlB   = -C_KMS * fstep * (1.0f / F_REST);   // km/s per subchannel
    const float invB  = fast_rcp(vlB);
    const float cA    = -vlA * invB;                        // fc (subch units)
    const float cgp   = pc2 * vlB * vlB;
    const float s     = sqrtf(cgp);

    // box-average moment match (sigma_e^2 = sigma^2 + 1.25 subch^2)
    const bool  use_box = (cgp <= 0.22f);
    const float cgp_e = cgp * fast_rcp(1.0f + 2.5f * LN2 * cgp);
    const float s_e   = sqrtf(cgp_e);
    const float dL    = 0.5f * __log2f(1.0f + 2.5f * LN2 * cgp);

    const float sSel = use_box ? s_e : s;
    const float qoff = use_box ? 1.5f : 0.0f;
    const float dLs  = use_box ? dL : 0.0f;
    const float sq   = sSel * qoff;

    // 16-wide window validity: 4.85*sigma_e_out <= 4.6 out-ch edge margin
    const bool win16 = use_box && (cgp_e >= 0.0502f);

    // ---- zero this wave's accumulators (wave-private, store-only) ----
    {
        float* ab = &accb[col][0][0][0];
        ab[lane] = 0.0f; ab[lane + 64] = 0.0f; ab[lane + 128] = 0.0f;
    }

    // ---- phase 1: geometry + z-band + segment classification ----
    const int i = (io << 1) + (col >> 1);
    const int j = (jo << 1) + (col & 1);
    const float x  = -FOV + dx * (float)i;
    const float y  = -FOV + dx * (float)j;
    const float rx = cr * x - sr * y;
    const float y1 = sr * x + cr * y;
    const float ciy1 = ci * y1, siy1 = si * y1;
    const float nsvrx = -si * vmax * rx;
    const float rx2   = rx * rx;
    const float rx2c  = rx2 + rc2pm;

    // z-band: alive => |rz| <= B  (rz = siy1 + ci*z), wave-uniform bounds
    const float B   = hz * sqrtf(2.0f * THR_P / LOG2E);
    const float rci = fast_rcp(ci);
    const float rdx = fast_rcp(dx);
    const float zlo = fminf((-B - siy1) * rci, (B - siy1) * rci);
    const float spanv = fabsf(2.0f * B * rci) * rdx;
    int niter = 3, klo0 = 0;
    if (spanv <= 124.0f) {
        const int kl = (int)floorf((zlo + FOV) * rdx) - 1;
        klo0 = min(max(kl, 0), 191);
        niter = 2;
    }

    float u_c[3], L_c[3];
    int   bk_c[3];
    #pragma unroll
    for (int c = 0; c < 3; ++c) {
        int bk = DEADB; float uu = 0.0f, nl = 100000.0f;
        if (c < niter) {                       // wave-uniform trip count
            const int kv = klo0 + c * 64 + lane;
            const float z  = __builtin_fmaf(dx, (float)kv, -FOV);
            const float ry = __builtin_fmaf(-si, z, ciy1);
            const float rz = __builtin_fmaf( ci, z, siy1);
            const float ry2 = ry * ry;
            const float R  = sqrtf(__builtin_fmaf(ry, ry, rx2));
            const float nL = __builtin_fmaf(R, kR, rz * rz * kz);
            const float inv  = __frsqrt_rn(ry2 + rx2c);
            const float vlos = nsvrx * inv;
            const float fc   = __builtin_fmaf(vlos, invB, cA);
            const bool alive = (nL <= THR_P);
            if (win16) {
                // k = clamp(round((fc_out-8)/8)); fc_out = (fc-1.5)/4
                int kk = (int)rintf(__builtin_fmaf(fc, 0.03125f, -1.046875f));
                kk = min(max(kk, 0), 2);
                if (alive) bk = kk;
            } else if (alive) bk = 3;
            uu = __builtin_fmaf(-fc, sSel, sq);        // sSel*(qoff - fc)
            nl = nL + dLs;
        }
        u_c[c] = uu; L_c[c] = nl; bk_c[c] = bk;
    }

    // pass A: ballots once, per-segment counts
    unsigned long long m_ck[3][4];
    int cnt[4];
    #pragma unroll
    for (int k = 0; k < 4; ++k) cnt[k] = 0;
    #pragma unroll
    for (int c = 0; c < 3; ++c)
        #pragma unroll
        for (int k = 0; k < 4; ++k) {
            const unsigned long long m = __ballot(bk_c[c] == k);
            m_ck[c][k] = m;
            cnt[k] += (int)__popcll(m);
        }

    int base[4];
    {
        int acc = 0;
        #pragma unroll
        for (int k = 0; k < 4; ++k) { base[k] = acc; acc += cnt[k] + 8; }
    }

    // pass B: scatter (rank via mbcnt)
    {
        int run[4] = {0, 0, 0, 0};
        #pragma unroll
        for (int c = 0; c < 3; ++c)
            #pragma unroll
            for (int k = 0; k < 4; ++k) {
                const unsigned long long m = m_ck[c][k];
                if (bk_c[c] == k)
                    pairs[col][base[k] + run[k] + lane_rank(m)] =
                        make_float2(u_c[c], L_c[c]);
                run[k] += (int)__popcll(m);
            }
    }
    #pragma unroll
    for (int k = 0; k < 4; ++k)   // 8 dead pads per segment (exp2 -> 0)
        if (lane < 8) pairs[col][base[k] + cnt[k] + lane] = make_float2(0.0f, 100000.0f);

    // ---- phase 2 (window path): 4 records per wave-iter, 16 lanes each ----
    if (win16) {
        const float w16 = (4.0f * sSel) * (float)l16;
        #pragma unroll
        for (int k = 0; k < 3; ++k) {
            if (cnt[k] > 0) {
                const float2* pr = &pairs[col][base[k]];
                const float wk = __builtin_fmaf((float)(32 * k), sSel, w16);
                float a0 = 0.0f, a1 = 0.0f;
                const int nOct = (cnt[k] + 7) >> 3;
                for (int t = 0; t < nOct; ++t) {
                    const float2 qA = pr[8 * t + g];        // records 8t+0..3
                    const float2 qB = pr[8 * t + 4 + g];    // records 8t+4..7
                    const float dA = wk + qA.x;
                    const float dB = wk + qB.x;
                    a0 += fast_exp2(-__builtin_fmaf(dA, dA, qA.y));
                    a1 += fast_exp2(-__builtin_fmaf(dB, dB, qB.y));
                }
                accb[col][k][g][l16] = a0 + a1;             // plain store, once
            }
        }
    } else {
        // fallback: 32-wide path (r11), records via 2 halves
        const float w4 = (4.0f * sSel) * (float)l32;
        const int nIter = (cnt[3] + 1) >> 1;
        const float2* bp = reinterpret_cast<const float2*>(
            reinterpret_cast<const char*>(&pairs[col][base[3]]) + (half << 3));
        float a0 = 0.0f, a1 = 0.0f;
        if (use_box) {
            for (int it = 0; it < nIter; it += 2) {
                const float2 qA = bp[2 * it];
                const float2 qB = bp[2 * it + 2];
                const float dA = w4 + qA.x;
                const float dB = w4 + qB.x;
                a0 += fast_exp2(-__builtin_fmaf(dA, dA, qA.y));
                a1 += fast_exp2(-__builtin_fmaf(dB, dB, qB.y));
            }
        } else {
            for (int it = 0; it < nIter; ++it) {
                const float2 q = bp[2 * it];
                const float db = w4 + q.x;
                #pragma unroll
                for (int fu = 0; fu < 4; ++fu) {
                    const float d = __builtin_fmaf((float)fu, sSel, db);
                    a0 += fast_exp2(-__builtin_fmaf(d, d, q.y));
                }
            }
        }
        accb[col][l32 >> 4][half][l32 & 15] = a0 + a1;      // plain store, once
    }
    __syncthreads();

    // ---- phase 3: fold -> 32 outputs ----
    if (tid < FOUT) {
        float ssum = 0.0f;
        if (win16) {
            #pragma unroll
            for (int k = 0; k < 3; ++k) {
                const int d = tid - 8 * k;
                if ((unsigned)d < 16u) {
                    #pragma unroll
                    for (int c2 = 0; c2 < 4; ++c2)
                        #pragma unroll
                        for (int gg = 0; gg < 4; ++gg)
                            ssum += accb[c2][k][gg][d];
                }
            }
        } else {
            #pragma unroll
            for (int c2 = 0; c2 < 4; ++c2)
                #pragma unroll
                for (int h = 0; h < 2; ++h)
                    ssum += accb[c2][tid >> 4][h][tid & 15];
        }
        const float normc = __frsqrt_rn(2.0f * 3.14159265358979f * sig_sq)
                          * (use_box ? 0.25f : 0.0625f);
        out[tid * (NOUT * NOUT) + io * NOUT + jo] = ssum * normc;
    }
}

extern "C" void kernel_launch(void* const* d_in, const int* in_sizes, int n_in,
                              void* d_out, int out_size, void* d_ws, size_t ws_size,
                              hipStream_t stream) {
    const float* p_inc  = (const float*)d_in[0];
    const float* p_rot  = (const float*)d_in[1];
    const float* p_lb   = (const float*)d_in[2];
    const float* p_vs   = (const float*)d_in[3];
    const float* p_vmax = (const float*)d_in[4];
    const float* p_rc   = (const float*)d_in[5];
    const float* p_Rd   = (const float*)d_in[6];
    const float* p_hz   = (const float*)d_in[7];
    const float* freqs  = (const float*)d_in[8];
    float* out = (float*)d_out;

    dim3 grid(NOUT, NOUT);
    dim3 block(256);
    cube_sim_kernel<<<grid, block, 0, stream>>>(p_inc, p_rot, p_lb, p_vs,
                                                p_vmax, p_rc, p_Rd, p_hz,
                                                freqs, out);
}

// Round 13
// 24.524 us; speedup vs baseline: 1.4081x; 1.0716x over previous
//
#include <hip/hip_runtime.h>
#include <math.h>

#define N_HI 192      // IMAGE_RES_OUT * IMAGE_UPSCALE
#define NOUT 96
#define FOUT 32
#define MAXP 194      // 192 records max + pad

__device__ __forceinline__ float fast_exp2(float x) {
#if __has_builtin(__builtin_amdgcn_exp2f)
    return __builtin_amdgcn_exp2f(x);
#else
    return exp2f(x);
#endif
}
__device__ __forceinline__ float fast_rcp(float x) {
#if __has_builtin(__builtin_amdgcn_rcpf)
    return __builtin_amdgcn_rcpf(x);
#else
    return 1.0f / x;
#endif
}
__device__ __forceinline__ int lane_rank(unsigned long long m) {
    return (int)__builtin_amdgcn_mbcnt_hi((unsigned)(m >> 32),
            __builtin_amdgcn_mbcnt_lo((unsigned)m, 0u));
}

__global__ __launch_bounds__(256) void cube_sim_kernel(
    const float* __restrict__ p_inc, const float* __restrict__ p_rot,
    const float* __restrict__ p_lb,  const float* __restrict__ p_vs,
    const float* __restrict__ p_vmax,const float* __restrict__ p_rc,
    const float* __restrict__ p_Rd,  const float* __restrict__ p_hz,
    const float* __restrict__ freqs, float* __restrict__ out)
{
    const int tid  = threadIdx.x;
    const int w    = tid >> 6;        // wave id = output pixel within 2x2 tile
    const int lane = tid & 63;
    const int half = lane >> 5;       // record parity this lane serves
    const int l32  = lane & 31;       // output channel this lane owns

    const int jo2 = 2 * blockIdx.x + (w & 1);   // output pixel coords
    const int io2 = 2 * blockIdx.y + (w >> 1);

    __shared__ alignas(16) float2 pairs[4][MAXP];  // wave-private compaction buf

    // ---- uniform scalar setup (ONCE per wave, amortized over 4 columns) ----
    const float FOV    = 500.0f;
    const float C_KMS  = 299792.458f;
    const float F_REST = 230.538f;
    const float LOG2E  = 1.4426950408889634f;
    const float LN2    = 0.6931471805599453f;

    const float inc    = *p_inc;
    const float rot    = *p_rot;
    const float lb     = *p_lb;
    const float vshift = *p_vs;
    const float vmax   = *p_vmax;
    const float rc     = *p_rc;
    const float Rd     = *p_Rd;
    const float hz     = *p_hz;
    const float f0     = freqs[0];
    const float f_last = freqs[FOUT - 1];

    const float cr = __cosf(rot), sr = __sinf(rot);
    const float ci = __cosf(inc), si = __sinf(inc);

    const float dx     = 2.0f * FOV / (float)(N_HI - 1);
    const float Rmin   = 0.1f * (2.0f * FOV / (float)N_HI);
    const float rc2pm  = rc * rc + Rmin * Rmin;
    const float sig_sq = lb * lb;
    const float pc2    = (0.5f * fast_rcp(sig_sq)) * LOG2E;
    const float kR     = LOG2E * fast_rcp(Rd);
    const float kz     = 0.5f * LOG2E * fast_rcp(hz * hz);
    const float THR_P  = 13.2877f;        // -log2(1e-4) survivor cutoff

    const float fstep = (f_last - f0) * (1.0f / 127.0f);
    const float vlA   = C_KMS * (1.0f - f0 * (1.0f / F_REST)) - vshift;
    const float vlB   = -C_KMS * fstep * (1.0f / F_REST);   // km/s per subchannel
    const float invB  = fast_rcp(vlB);
    const float cA    = -vlA * invB;                        // fc (subch units)
    const float cgp   = pc2 * vlB * vlB;
    const float s     = sqrtf(cgp);

    // box-average moment match (sigma_e^2 = sigma^2 + 1.25 subch^2)
    const bool  use_box = (cgp <= 0.22f);
    const float cgp_e = cgp * fast_rcp(1.0f + 2.5f * LN2 * cgp);
    const float s_e   = sqrtf(cgp_e);
    const float dL    = 0.5f * __log2f(1.0f + 2.5f * LN2 * cgp);

    const float sSel = use_box ? s_e : s;
    const float qoff = use_box ? 1.5f : 0.0f;
    const float dLs  = use_box ? dL : 0.0f;
    const float sq   = sSel * qoff;

    // z-band uniforms (exact: alive => |rz| <= Bz); niter=2 needs klo0 <= 64
    const float Bz    = hz * sqrtf(2.0f * THR_P / LOG2E);
    const float rci   = fast_rcp(ci);
    const float rdx   = fast_rcp(dx);
    const float spanu = fabsf(2.0f * Bz * rci) * rdx;
    const bool  band2 = (spanu <= 124.0f);

    const float w4 = (4.0f * sSel) * (float)l32;   // lane's channel coordinate

    float a0 = 0.0f, a1 = 0.0f;                    // carried across all 4 columns

    // ================= per-column loop (4 hi-res columns of this pixel) ======
    for (int c2 = 0; c2 < 4; ++c2) {
        const int i = 2 * io2 + (c2 >> 1);
        const int j = 2 * jo2 + (c2 & 1);
        const float x  = __builtin_fmaf(dx, (float)i, -FOV);
        const float y  = __builtin_fmaf(dx, (float)j, -FOV);
        const float rx = cr * x - sr * y;
        const float y1 = sr * x + cr * y;
        const float ciy1 = ci * y1, siy1 = si * y1;
        const float nsvrx = -si * vmax * rx;
        const float rx2   = rx * rx;
        const float rx2c  = rx2 + rc2pm;

        int niter = 3, klo0 = 0;
        if (band2) {
            const float zlo = fminf((-Bz - siy1) * rci, (Bz - siy1) * rci);
            const int kl = (int)floorf((zlo + FOV) * rdx) - 1;
            klo0 = min(max(kl, 0), 64);   // kv <= 191: no phantom voxels (r12 fix)
            niter = 2;
        }

        // ---- phase 1: geometry -> compacted (qo, nL') records ----
        int cnt = 0;
        for (int c = 0; c < niter; ++c) {
            const int kv = klo0 + c * 64 + lane;
            const float z  = __builtin_fmaf(dx, (float)kv, -FOV);
            const float ry = __builtin_fmaf(-si, z, ciy1);
            const float rz = __builtin_fmaf( ci, z, siy1);
            const float ry2 = ry * ry;
            const float R  = sqrtf(__builtin_fmaf(ry, ry, rx2));
            const float nL = __builtin_fmaf(R, kR, rz * rz * kz);
            const float inv  = __frsqrt_rn(ry2 + rx2c);
            const float vlos = nsvrx * inv;
            const float fc   = __builtin_fmaf(vlos, invB, cA);
            const bool alive = (nL <= THR_P);
            const unsigned long long m = __ballot(alive);
            if (alive) {
                const float qo = __builtin_fmaf(-fc, sSel, sq);  // sSel*(qoff-fc)
                pairs[w][cnt + lane_rank(m)] = make_float2(qo, nL + dLs);
            }
            cnt += (int)__popcll(m);
        }
        if (lane == 0) pairs[w][cnt] = make_float2(0.0f, 100000.0f);  // dead pad

        // ---- phase 2: 2 records/iter; lane serves record `half` on channel l32 ----
        const int nIter = (cnt + 1) >> 1;
        const float2* bp = reinterpret_cast<const float2*>(
            reinterpret_cast<const char*>(&pairs[w][0]) + (half << 3));
        if (use_box) {
            int it = 0;
            for (; it + 2 <= nIter; it += 2) {
                const float2 qA = bp[2 * it];        // broadcast per half: free
                const float2 qB = bp[2 * it + 2];
                const float dA = w4 + qA.x;
                const float dB = w4 + qB.x;
                a0 += fast_exp2(-__builtin_fmaf(dA, dA, qA.y));
                a1 += fast_exp2(-__builtin_fmaf(dB, dB, qB.y));
            }
            if (it < nIter) {
                const float2 qA = bp[2 * it];
                const float dA = w4 + qA.x;
                a0 += fast_exp2(-__builtin_fmaf(dA, dA, qA.y));
            }
        } else {
            // exact 4-subchannel fallback (narrow line widths only)
            for (int it = 0; it < nIter; ++it) {
                const float2 q = bp[2 * it];
                const float db = w4 + q.x;
                #pragma unroll
                for (int fu = 0; fu < 4; ++fu) {
                    const float d = __builtin_fmaf((float)fu, sSel, db);
                    a0 += fast_exp2(-__builtin_fmaf(d, d, q.y));
                }
            }
        }
    }

    // ---- final: fold the two record-halves across lane^32, store 32 channels ----
    float asum = a0 + a1;
    asum += __shfl_xor(asum, 32, 64);
    if (lane < FOUT) {
        const float normc = __frsqrt_rn(2.0f * 3.14159265358979f * sig_sq)
                          * (use_box ? 0.25f : 0.0625f);
        out[lane * (NOUT * NOUT) + io2 * NOUT + jo2] = asum * normc;
    }
}

extern "C" void kernel_launch(void* const* d_in, const int* in_sizes, int n_in,
                              void* d_out, int out_size, void* d_ws, size_t ws_size,
                              hipStream_t stream) {
    const float* p_inc  = (const float*)d_in[0];
    const float* p_rot  = (const float*)d_in[1];
    const float* p_lb   = (const float*)d_in[2];
    const float* p_vs   = (const float*)d_in[3];
    const float* p_vmax = (const float*)d_in[4];
    const float* p_rc   = (const float*)d_in[5];
    const float* p_Rd   = (const float*)d_in[6];
    const float* p_hz   = (const float*)d_in[7];
    const float* freqs  = (const float*)d_in[8];
    float* out = (float*)d_out;

    dim3 grid(NOUT / 2, NOUT / 2);
    dim3 block(256);
    cube_sim_kernel<<<grid, block, 0, stream>>>(p_inc, p_rot, p_lb, p_vs,
                                                p_vmax, p_rc, p_Rd, p_hz,
                                                freqs, out);
}

// Round 14
// 23.774 us; speedup vs baseline: 1.4525x; 1.0315x over previous
//
#include <hip/hip_runtime.h>
#include <math.h>

#define N_HI 192      // IMAGE_RES_OUT * IMAGE_UPSCALE
#define NOUT 96
#define FOUT 32
#define MAXPG 390     // 2 cols x 192 records max + pads

__device__ __forceinline__ float fast_exp2(float x) {
#if __has_builtin(__builtin_amdgcn_exp2f)
    return __builtin_amdgcn_exp2f(x);
#else
    return exp2f(x);
#endif
}
__device__ __forceinline__ float fast_rcp(float x) {
#if __has_builtin(__builtin_amdgcn_rcpf)
    return __builtin_amdgcn_rcpf(x);
#else
    return 1.0f / x;
#endif
}
__device__ __forceinline__ int lane_rank(unsigned long long m) {
    return (int)__builtin_amdgcn_mbcnt_hi((unsigned)(m >> 32),
            __builtin_amdgcn_mbcnt_lo((unsigned)m, 0u));
}

__global__ __launch_bounds__(256) void cube_sim_kernel(
    const float* __restrict__ p_inc, const float* __restrict__ p_rot,
    const float* __restrict__ p_lb,  const float* __restrict__ p_vs,
    const float* __restrict__ p_vmax,const float* __restrict__ p_rc,
    const float* __restrict__ p_Rd,  const float* __restrict__ p_hz,
    const float* __restrict__ freqs, float* __restrict__ out)
{
    const int tid  = threadIdx.x;
    const int w    = tid >> 6;        // wave id = output pixel within 2x2 tile
    const int lane = tid & 63;
    const int half = lane >> 5;       // record parity this lane serves
    const int l32  = lane & 31;       // output channel this lane owns

    const int jo2 = 2 * blockIdx.x + (w & 1);   // output pixel coords
    const int io2 = 2 * blockIdx.y + (w >> 1);

    __shared__ alignas(16) float2 pairs[4][MAXPG];  // wave-private record stream

    // ---- uniform scalar setup (once per wave, amortized over 4 columns) ----
    const float FOV    = 500.0f;
    const float C_KMS  = 299792.458f;
    const float F_REST = 230.538f;
    const float LOG2E  = 1.4426950408889634f;
    const float LN2    = 0.6931471805599453f;

    const float inc    = *p_inc;
    const float rot    = *p_rot;
    const float lb     = *p_lb;
    const float vshift = *p_vs;
    const float vmax   = *p_vmax;
    const float rc     = *p_rc;
    const float Rd     = *p_Rd;
    const float hz     = *p_hz;
    const float f0     = freqs[0];
    const float f_last = freqs[FOUT - 1];

    const float cr = __cosf(rot), sr = __sinf(rot);
    const float ci = __cosf(inc), si = __sinf(inc);

    const float dx     = 2.0f * FOV / (float)(N_HI - 1);
    const float Rmin   = 0.1f * (2.0f * FOV / (float)N_HI);
    const float rc2pm  = rc * rc + Rmin * Rmin;
    const float sig_sq = lb * lb;
    const float pc2    = (0.5f * fast_rcp(sig_sq)) * LOG2E;
    const float kR     = LOG2E * fast_rcp(Rd);
    const float kz     = 0.5f * LOG2E * fast_rcp(hz * hz);
    const float THR_P  = 13.2877f;        // -log2(1e-4) survivor cutoff

    const float fstep = (f_last - f0) * (1.0f / 127.0f);
    const float vlA   = C_KMS * (1.0f - f0 * (1.0f / F_REST)) - vshift;
    const float vlB   = -C_KMS * fstep * (1.0f / F_REST);   // km/s per subchannel
    const float invB  = fast_rcp(vlB);
    const float cA    = -vlA * invB;                        // fc (subch units)
    const float cgp   = pc2 * vlB * vlB;
    const float s     = sqrtf(cgp);

    // box-average moment match (sigma_e^2 = sigma^2 + 1.25 subch^2)
    const bool  use_box = (cgp <= 0.22f);
    const float cgp_e = cgp * fast_rcp(1.0f + 2.5f * LN2 * cgp);
    const float s_e   = sqrtf(cgp_e);
    const float dL    = 0.5f * __log2f(1.0f + 2.5f * LN2 * cgp);

    const float sSel = use_box ? s_e : s;
    const float qoff = use_box ? 1.5f : 0.0f;
    const float dLs  = use_box ? dL : 0.0f;
    const float sq   = sSel * qoff;

    // z-band uniforms (exact: alive => |rz| <= Bz); niter=2 needs klo0 <= 64
    const float Bz    = hz * sqrtf(2.0f * THR_P / LOG2E);
    const float rci   = fast_rcp(ci);
    const float rdx   = fast_rcp(dx);
    const float spanu = fabsf(2.0f * Bz * rci) * rdx;
    const bool  band2 = (spanu <= 124.0f);

    const float w4 = (4.0f * sSel) * (float)l32;   // lane's channel coordinate

    float a0 = 0.0f, a1 = 0.0f;                    // carried across all columns

    // ============ two groups of 2 columns; merged record stream each ========
    #pragma unroll
    for (int grp = 0; grp < 2; ++grp) {
        // ---- phase 1: append 2 columns' records into one stream ----
        int cnt = 0;
        #pragma unroll
        for (int cc = 0; cc < 2; ++cc) {
            const int c4 = 2 * grp + cc;
            const int i = 2 * io2 + (c4 >> 1);
            const int j = 2 * jo2 + (c4 & 1);
            const float x  = __builtin_fmaf(dx, (float)i, -FOV);
            const float y  = __builtin_fmaf(dx, (float)j, -FOV);
            const float rx = cr * x - sr * y;
            const float y1 = sr * x + cr * y;
            const float ciy1 = ci * y1, siy1 = si * y1;
            const float nsvrx = -si * vmax * rx;
            const float rx2   = rx * rx;
            const float rx2c  = rx2 + rc2pm;

            int niter = 3, klo0 = 0;
            if (band2) {
                const float zlo = fminf((-Bz - siy1) * rci, (Bz - siy1) * rci);
                const int kl = (int)floorf((zlo + FOV) * rdx) - 1;
                klo0 = min(max(kl, 0), 64);   // kv <= 191: no phantom voxels
                niter = 2;
            }

            for (int c = 0; c < niter; ++c) {
                const int kv = klo0 + c * 64 + lane;
                const float z  = __builtin_fmaf(dx, (float)kv, -FOV);
                const float ry = __builtin_fmaf(-si, z, ciy1);
                const float rz = __builtin_fmaf( ci, z, siy1);
                const float ry2 = ry * ry;
                const float R  = sqrtf(__builtin_fmaf(ry, ry, rx2));
                const float nL = __builtin_fmaf(R, kR, rz * rz * kz);
                const float inv  = __frsqrt_rn(ry2 + rx2c);
                const float vlos = nsvrx * inv;
                const float fc   = __builtin_fmaf(vlos, invB, cA);
                const bool alive = (nL <= THR_P);
                const unsigned long long m = __ballot(alive);
                if (alive) {
                    const float qo = __builtin_fmaf(-fc, sSel, sq); // sSel*(qoff-fc)
                    pairs[w][cnt + lane_rank(m)] = make_float2(qo, nL + dLs);
                }
                cnt += (int)__popcll(m);
            }
        }
        if (lane == 0) pairs[w][cnt] = make_float2(0.0f, 100000.0f);  // dead pad

        // ---- phase 2: one long loop; lane serves record `half` on channel l32 ----
        const int nIter = (cnt + 1) >> 1;
        const float2* bp = reinterpret_cast<const float2*>(
            reinterpret_cast<const char*>(&pairs[w][0]) + (half << 3));
        if (use_box) {
            int it = 0;
            for (; it + 2 <= nIter; it += 2) {
                const float2 qA = bp[2 * it];        // broadcast per half
                const float2 qB = bp[2 * it + 2];
                const float dA = w4 + qA.x;
                const float dB = w4 + qB.x;
                a0 += fast_exp2(-__builtin_fmaf(dA, dA, qA.y));
                a1 += fast_exp2(-__builtin_fmaf(dB, dB, qB.y));
            }
            if (it < nIter) {
                const float2 qA = bp[2 * it];
                const float dA = w4 + qA.x;
                a0 += fast_exp2(-__builtin_fmaf(dA, dA, qA.y));
            }
        } else {
            // exact 4-subchannel fallback (narrow line widths only)
            for (int it = 0; it < nIter; ++it) {
                const float2 q = bp[2 * it];
                const float db = w4 + q.x;
                #pragma unroll
                for (int fu = 0; fu < 4; ++fu) {
                    const float d = __builtin_fmaf((float)fu, sSel, db);
                    a0 += fast_exp2(-__builtin_fmaf(d, d, q.y));
                }
            }
        }
    }

    // ---- final: fold the two record-halves across lane^32, store 32 channels ----
    float asum = a0 + a1;
    asum += __shfl_xor(asum, 32, 64);
    if (lane < FOUT) {
        const float normc = __frsqrt_rn(2.0f * 3.14159265358979f * sig_sq)
                          * (use_box ? 0.25f : 0.0625f);
        out[lane * (NOUT * NOUT) + io2 * NOUT + jo2] = asum * normc;
    }
}

extern "C" void kernel_launch(void* const* d_in, const int* in_sizes, int n_in,
                              void* d_out, int out_size, void* d_ws, size_t ws_size,
                              hipStream_t stream) {
    const float* p_inc  = (const float*)d_in[0];
    const float* p_rot  = (const float*)d_in[1];
    const float* p_lb   = (const float*)d_in[2];
    const float* p_vs   = (const float*)d_in[3];
    const float* p_vmax = (const float*)d_in[4];
    const float* p_rc   = (const float*)d_in[5];
    const float* p_Rd   = (const float*)d_in[6];
    const float* p_hz   = (const float*)d_in[7];
    const float* freqs  = (const float*)d_in[8];
    float* out = (float*)d_out;

    dim3 grid(NOUT / 2, NOUT / 2);
    dim3 block(256);
    cube_sim_kernel<<<grid, block, 0, stream>>>(p_inc, p_rot, p_lb, p_vs,
                                                p_vmax, p_rc, p_Rd, p_hz,
                                                freqs, out);
}